// Round 1
// baseline (1397.873 us; speedup 1.0000x reference)
//
#include <hip/hip_runtime.h>

// Exact 16-NN: b=8 batches, n=16384 source pts (xyz1), m=8192 queries (xyz2).
// Output int32 indices (b, m, 16, 1), nearest-first, ties -> lower index.
//
// Numerics: must match reference f32 ordering bit-exactly.
//   d = (q2 + p2) - 2*dot
//   q2,p2 = ((x*x + y*y) + z*z)   plain rounded ops (no FMA contraction)
//   dot   = fma(pz,qz, fma(py,qy, round(px*qx)))   (BLAS-style k-ascending FMA)
//   final = fma(-2, dot, q2+p2)  == (q2+p2) - 2*dot exactly (x2 is exact)

#define KNN_K   16
#define NPTS    16384
#define MQ      8192
#define NBATCH  8
#define TILE    4096
#define BLOCK   256

__global__ __launch_bounds__(BLOCK, 1) void knn16_kernel(
    const float* __restrict__ xyz1,   // (B, NPTS, 3)
    const float* __restrict__ xyz2,   // (B, MQ, 3)
    int* __restrict__ out)            // (B, MQ, K)
{
    __shared__ float4 pts[TILE];      // x, y, z, p2  (64 KiB)

    const int b  = blockIdx.x >> 5;                       // 32 blocks per batch
    const int qi = ((blockIdx.x & 31) * BLOCK) + threadIdx.x;

    const float* p1 = xyz1 + (size_t)b * NPTS * 3;
    const float* qp = xyz2 + ((size_t)b * MQ + qi) * 3;

    const float qx = qp[0], qy = qp[1], qz = qp[2];
    const float q2 = __fadd_rn(__fadd_rn(__fmul_rn(qx, qx), __fmul_rn(qy, qy)),
                               __fmul_rn(qz, qz));

    float dist[KNN_K];
    int   idx [KNN_K];
#pragma unroll
    for (int i = 0; i < KNN_K; ++i) { dist[i] = INFINITY; idx[i] = 0; }

    for (int t0 = 0; t0 < NPTS; t0 += TILE) {
        __syncthreads();   // previous tile fully consumed before overwrite
        // ---- stage tile: 256 threads x 16 points, compute p2 with reference rounding
        for (int i = threadIdx.x; i < TILE; i += BLOCK) {
            const float* p = p1 + (size_t)(t0 + i) * 3;
            const float x = p[0], y = p[1], z = p[2];
            const float p2 = __fadd_rn(__fadd_rn(__fmul_rn(x, x), __fmul_rn(y, y)),
                                       __fmul_rn(z, z));
            pts[i] = make_float4(x, y, z, p2);
        }
        __syncthreads();

        // ---- scan tile (wave-uniform LDS broadcast reads)
#pragma unroll 4
        for (int j = 0; j < TILE; ++j) {
            const float4 p = pts[j];
            const float dot = __builtin_fmaf(p.z, qz,
                              __builtin_fmaf(p.y, qy,
                              __fmul_rn(p.x, qx)));
            const float d = __builtin_fmaf(-2.0f, dot, __fadd_rn(q2, p.w));
            if (d < dist[KNN_K - 1]) {                    // strict: stable ties
                dist[KNN_K - 1] = d;
                idx [KNN_K - 1] = t0 + j;
                // single bubble pass: only the tail element is out of order
#pragma unroll
                for (int i = KNN_K - 1; i >= 1; --i) {
                    const bool sw = dist[i] < dist[i - 1];  // strict: stability
                    const float td = dist[i]; const int ti = idx[i];
                    dist[i]     = sw ? dist[i - 1] : dist[i];
                    idx [i]     = sw ? idx [i - 1] : idx [i];
                    dist[i - 1] = sw ? td : dist[i - 1];
                    idx [i - 1] = sw ? ti : idx [i - 1];
                }
            }
        }
    }

    int* o = out + ((size_t)b * MQ + qi) * KNN_K;
#pragma unroll
    for (int i = 0; i < KNN_K; ++i) o[i] = idx[i];
}

extern "C" void kernel_launch(void* const* d_in, const int* in_sizes, int n_in,
                              void* d_out, int out_size, void* d_ws, size_t ws_size,
                              hipStream_t stream) {
    const float* xyz1 = (const float*)d_in[0];
    const float* xyz2 = (const float*)d_in[1];
    int* out = (int*)d_out;
    // 8 batches * 32 blocks, 256 threads: one thread per query
    knn16_kernel<<<dim3(NBATCH * 32), dim3(BLOCK), 0, stream>>>(xyz1, xyz2, out);
}